// Round 10
// baseline (270.895 us; speedup 1.0000x reference)
//
#include <hip/hip_runtime.h>
#include <math.h>

#define N_AG 8192
#define SD 64
#define HD 128
#define CD 32
#define AD 8
#define NBLK 512
#define MAGIC1 0x13571357u
#define MAGIC2 0x24682468u

// ws layout: u32 region for barrier state, then float region
#define FLAG1_OFF 0                 // 512 u32
#define FLAG2_OFF 512               // 512 u32
#define GO_OFF    1024              // 2 u32
#define MPART_OFF 1032              // NBLK*CD floats (16B-aligned: 1032*4=4128)
#define HSUM_OFF  (MPART_OFF + NBLK*CD)   // 128 floats

#define FMA4(acc, xv, w0, w1, w2, w3)                                   \
    acc.x += xv.x*w0.x + xv.y*w1.x + xv.z*w2.x + xv.w*w3.x;             \
    acc.y += xv.x*w0.y + xv.y*w1.y + xv.z*w2.y + xv.w*w3.y;             \
    acc.z += xv.x*w0.z + xv.y*w1.z + xv.z*w2.z + xv.w*w3.z;             \
    acc.w += xv.x*w0.w + xv.y*w1.w + xv.z*w2.w + xv.w*w3.w;

// Poison-robust grid barrier: per-block magic flags + master(block0) scan + go broadcast.
// All signalling via device-scope atomics; never depends on ws initial contents.
__device__ __forceinline__ void grid_barrier(unsigned* __restrict__ flags,
                                             unsigned* __restrict__ go,
                                             unsigned magic, int b, int t) {
    __syncthreads();                 // all block work (incl. its atomics) issued
    __threadfence();                 // publish this thread's prior writes
    if (t == 0) atomicExch(&flags[b], magic);
    if (b == 0) {
        for (int s = t; s < NBLK; s += 256) {
            while (atomicAdd(&flags[s], 0u) != magic) __builtin_amdgcn_s_sleep(2);
        }
        __syncthreads();
        if (t == 0) atomicExch(go, magic);
    }
    if (t == 0) {
        while (atomicAdd(go, 0u) != magic) __builtin_amdgcn_s_sleep(8);
    }
    __syncthreads();
    __threadfence();
}

__global__ __launch_bounds__(256, 2)
void fused_mas(const float* __restrict__ X, const float* __restrict__ noise,
               const float* __restrict__ W1, const float* __restrict__ b1,
               const float* __restrict__ W2, const float* __restrict__ b2,
               const float* __restrict__ Wc, const float* __restrict__ bc,
               const float* __restrict__ Wg, const float* __restrict__ bg,
               const float* __restrict__ Wp, const float* __restrict__ bp,
               const float* __restrict__ Wv, const float* __restrict__ bv,
               const float* __restrict__ Wr, const float* __restrict__ br,
               float* __restrict__ ws, float* __restrict__ out)
{
    unsigned* wsu   = (unsigned*)ws;
    unsigned* flag1 = wsu + FLAG1_OFF;
    unsigned* flag2 = wsu + FLAG2_OFF;
    unsigned* go    = wsu + GO_OFF;
    float*    mpart = ws + MPART_OFF;
    float*    hsum  = ws + HSUM_OFF;

    __shared__ float4 sX4[16][16];
    __shared__ float4 sP4[16][32];       // raw P
    __shared__ float4 sT4[16][32];       // relu(P)
    __shared__ float4 sU4[16][32];       // U = relu(P)@W2 + b2
    __shared__ float  sMg[16][CD];
    __shared__ float  sPart[8][CD];
    __shared__ float  sMsum[CD];
    __shared__ __align__(16) float sC[HD];
    __shared__ float4 sRed[8][32];
    __shared__ __align__(16) float sA[HD];
    __shared__ __align__(16) float sB[HD];
    __shared__ __align__(16) float sG[HD];
    __shared__ __align__(16) float sWT[12][HD + 4];
    __shared__ float sBall[12];
    __shared__ __align__(16) float4 sH4[16][33];

    const int t = threadIdx.x;
    const int b = blockIdx.x;
    const int a0 = b * 16;

    // ---- stage head weights (tiny) + X tile; block 0 zeroes hsum coherently
    for (int idx = t; idx < 12 * HD; idx += 256) {
        int j = idx >> 7, k = idx & 127;
        sWT[j][k] = (j < 8) ? Wp[k*AD + j] : (j == 8) ? Wv[k] : Wr[k*3 + (j - 9)];
    }
    if (t < 12) sBall[t] = (t < 8) ? bp[t] : (t == 8) ? bv[0] : br[t - 9];
    { int ag = t >> 4, k4 = t & 15; sX4[ag][k4] = ((const float4*)X)[(a0 + ag)*16 + k4]; }
    if (b == 0 && t < HD) atomicExch(&hsum[t], 0.f);
    __syncthreads();

    const int c4 = t & 31, A0 = t >> 5, A1 = A0 + 8;
    // ======== phase 1a: P = X@W1a + b1  (kept in LDS, raw + relu)
    {
        float4 bb = ((const float4*)b1)[c4];
        float4 p0 = bb, p1 = bb;
        #pragma unroll
        for (int k4 = 0; k4 < 16; ++k4) {
            float4 xA = sX4[A0][k4], xB = sX4[A1][k4];
            float4 w0 = ((const float4*)(W1 + (4*k4 + 0)*HD))[c4];
            float4 w1 = ((const float4*)(W1 + (4*k4 + 1)*HD))[c4];
            float4 w2 = ((const float4*)(W1 + (4*k4 + 2)*HD))[c4];
            float4 w3 = ((const float4*)(W1 + (4*k4 + 3)*HD))[c4];
            FMA4(p0, xA, w0, w1, w2, w3);
            FMA4(p1, xB, w0, w1, w2, w3);
        }
        sP4[A0][c4] = p0;
        sP4[A1][c4] = p1;
        float4 r0, r1;
        r0.x = fmaxf(p0.x, 0.f); r0.y = fmaxf(p0.y, 0.f); r0.z = fmaxf(p0.z, 0.f); r0.w = fmaxf(p0.w, 0.f);
        r1.x = fmaxf(p1.x, 0.f); r1.y = fmaxf(p1.y, 0.f); r1.z = fmaxf(p1.z, 0.f); r1.w = fmaxf(p1.w, 0.f);
        sT4[A0][c4] = r0;
        sT4[A1][c4] = r1;
    }
    __syncthreads();
    // ======== phase 1b: U = relu(P)@W2 + b2
    {
        float4 b2v = ((const float4*)b2)[c4];
        float4 u0 = b2v, u1 = b2v;
        #pragma unroll
        for (int k4 = 0; k4 < 32; ++k4) {
            float4 tA = sT4[A0][k4], tB = sT4[A1][k4];
            float4 w0 = ((const float4*)(W2 + (4*k4 + 0)*HD))[c4];
            float4 w1 = ((const float4*)(W2 + (4*k4 + 1)*HD))[c4];
            float4 w2 = ((const float4*)(W2 + (4*k4 + 2)*HD))[c4];
            float4 w3 = ((const float4*)(W2 + (4*k4 + 3)*HD))[c4];
            FMA4(u0, tA, w0, w1, w2, w3);
            FMA4(u1, tB, w0, w1, w2, w3);
        }
        sU4[A0][c4] = u0;
        sU4[A1][c4] = u1;
    }
    __syncthreads();
    // ======== phase 1c: M = U@Wc + bc, l2norm, per-block msum partial -> mpart[b]
    {
        float m0 = bc[c4], m1 = m0;
        #pragma unroll 8
        for (int k4 = 0; k4 < 32; ++k4) {
            float4 uA = sU4[A0][k4], uB = sU4[A1][k4];
            float w0 = Wc[(4*k4 + 0)*CD + c4];
            float w1 = Wc[(4*k4 + 1)*CD + c4];
            float w2 = Wc[(4*k4 + 2)*CD + c4];
            float w3 = Wc[(4*k4 + 3)*CD + c4];
            m0 += uA.x*w0 + uA.y*w1 + uA.z*w2 + uA.w*w3;
            m1 += uB.x*w0 + uB.y*w1 + uB.z*w2 + uB.w*w3;
        }
        float ss0 = m0*m0, ss1 = m1*m1;
        #pragma unroll
        for (int off = 1; off < 32; off <<= 1) {
            ss0 += __shfl_xor(ss0, off);
            ss1 += __shfl_xor(ss1, off);
        }
        sMg[A0][c4] = m0 * (1.f / fmaxf(sqrtf(ss0), 1e-12f));
        sMg[A1][c4] = m1 * (1.f / fmaxf(sqrtf(ss1), 1e-12f));
    }
    __syncthreads();
    if (t < CD) {
        float s = 0.f;
        #pragma unroll
        for (int ag = 0; ag < 16; ++ag) s += sMg[ag][t];
        atomicExch(&mpart[b*CD + t], s);    // device-coherent publish
    }

    grid_barrier(flag1, &go[0], MAGIC1, b, t);

    // ======== phase 2: msum reduce (redundant/block), cvec, hsum partial
    {
        const int c = t & 31, chunk = t >> 5;
        float s = 0.f;
        for (int p = chunk*64; p < chunk*64 + 64; ++p)
            s += mpart[p*CD + c];           // first-touch reads, writers atomic
        sPart[chunk][c] = s;
    }
    __syncthreads();
    if (t < CD) {
        float s = 0.f;
        #pragma unroll
        for (int j = 0; j < 8; ++j) s += sPart[j][t];
        sMsum[t] = s;
    }
    __syncthreads();
    if (t < HD) {
        float s = 0.f;
        #pragma unroll
        for (int k = 0; k < CD; ++k) s += sMsum[k] * W1[(SD + k)*HD + t];
        sC[t] = s * (1.f / (float)N_AG);
    }
    __syncthreads();
    {
        float4 cv = ((const float4*)sC)[c4];
        float4 acc; acc.x = acc.y = acc.z = acc.w = 0.f;
        #pragma unroll
        for (int i = 0; i < 2; ++i) {
            int ag = A0 + i*8;              // A0 in [0,8): agents A0, A0+8
            float4 p = sP4[ag][c4];
            acc.x += fmaxf(p.x + cv.x, 0.f);
            acc.y += fmaxf(p.y + cv.y, 0.f);
            acc.z += fmaxf(p.z + cv.z, 0.f);
            acc.w += fmaxf(p.w + cv.w, 0.f);
        }
        sRed[A0][c4] = acc;
    }
    __syncthreads();
    if (t < 32) {
        float4 s = sRed[0][t];
        #pragma unroll
        for (int gg = 1; gg < 8; ++gg) {
            float4 v = sRed[gg][t];
            s.x += v.x; s.y += v.y; s.z += v.z; s.w += v.w;
        }
        atomicAdd(&hsum[4*t + 0], s.x);
        atomicAdd(&hsum[4*t + 1], s.y);
        atomicAdd(&hsum[4*t + 2], s.z);
        atomicAdd(&hsum[4*t + 3], s.w);
    }

    grid_barrier(flag2, &go[1], MAGIC2, b, t);

    // ======== phase 3: g = relu(((hsum/N)@W2 + b2)@Wg + bg)  (redundant per block)
    if (t < HD) sA[t] = hsum[t] * (1.f / (float)N_AG);
    __syncthreads();
    if (t < HD) {
        float s = b2[t];
        #pragma unroll 16
        for (int k = 0; k < HD; ++k) s += sA[k] * W2[k*HD + t];
        sB[t] = s;
    }
    __syncthreads();
    if (t < HD) {
        float s = bg[t];
        #pragma unroll 16
        for (int k = 0; k < HD; ++k) s += sB[k] * Wg[k*HD + t];
        sG[t] = fmaxf(s, 0.f);
    }
    __syncthreads();

    // ======== phase 4: per-agent normalize + heads (16 threads/agent)
    const int ag = t >> 4, q = t & 15;
    const int a = a0 + ag;
    float4 n0 = ((const float4*)noise)[a*32 + q*2];
    float4 n1 = ((const float4*)noise)[a*32 + q*2 + 1];
    float4 g0 = ((const float4*)sG)[q*2];
    float4 g1 = ((const float4*)sG)[q*2 + 1];
    float4 v0, v1;
    v0.x = g0.x + 0.01f*n0.x; v0.y = g0.y + 0.01f*n0.y; v0.z = g0.z + 0.01f*n0.z; v0.w = g0.w + 0.01f*n0.w;
    v1.x = g1.x + 0.01f*n1.x; v1.y = g1.y + 0.01f*n1.y; v1.z = g1.z + 0.01f*n1.z; v1.w = g1.w + 0.01f*n1.w;
    float ss = v0.x*v0.x + v0.y*v0.y + v0.z*v0.z + v0.w*v0.w
             + v1.x*v1.x + v1.y*v1.y + v1.z*v1.z + v1.w*v1.w;
    #pragma unroll
    for (int off = 1; off < 16; off <<= 1) ss += __shfl_xor(ss, off);
    float rinv = 1.f / fmaxf(sqrtf(ss), 1e-12f);
    float4 h0, h1;
    h0.x = v0.x*rinv; h0.y = v0.y*rinv; h0.z = v0.z*rinv; h0.w = v0.w*rinv;
    h1.x = v1.x*rinv; h1.y = v1.y*rinv; h1.z = v1.z*rinv; h1.w = v1.w*rinv;
    ((float4*)out)[a*32 + q*2]     = h0;
    ((float4*)out)[a*32 + q*2 + 1] = h1;
    sH4[ag][q*2]     = h0;
    sH4[ag][q*2 + 1] = h1;
    __syncthreads();
    float acc = 0.f;
    if (q < 12) {
        acc = sBall[q];
        const float4* wT = (const float4*)&sWT[q][0];
        #pragma unroll
        for (int k4 = 0; k4 < 32; ++k4) {
            float4 hh = sH4[ag][k4];
            float4 w  = wT[k4];
            acc += hh.x*w.x + hh.y*w.y + hh.z*w.z + hh.w*w.w;
        }
    }
    int base = (t & 63) & ~15;
    float a9  = __shfl(acc, base + 9, 64);
    float a10 = __shfl(acc, base + 10, 64);
    float a11 = __shfl(acc, base + 11, 64);
    float* outA = out + N_AG*HD;
    float* outV = outA + N_AG*AD;
    float* outR = outV + N_AG;
    if (q < 8) {
        outA[a*AD + q] = tanhf(acc);
    } else if (q == 8) {
        outV[a] = acc;
    } else if (q < 12) {
        float m = fmaxf(a9, fmaxf(a10, a11));
        float d = expf(a9 - m) + expf(a10 - m) + expf(a11 - m);
        outR[a*3 + (q - 9)] = expf(acc - m) / d;
    }
}

extern "C" void kernel_launch(void* const* d_in, const int* in_sizes, int n_in,
                              void* d_out, int out_size, void* d_ws, size_t ws_size,
                              hipStream_t stream) {
    const float* states = (const float*)d_in[0];
    const float* noise  = (const float*)d_in[1];
    const float* W1 = (const float*)d_in[2];
    const float* b1 = (const float*)d_in[3];
    const float* W2 = (const float*)d_in[4];
    const float* b2 = (const float*)d_in[5];
    const float* Wc = (const float*)d_in[6];
    const float* bc = (const float*)d_in[7];
    const float* Wg = (const float*)d_in[8];
    const float* bg = (const float*)d_in[9];
    const float* Wp = (const float*)d_in[10];
    const float* bp = (const float*)d_in[11];
    const float* Wv = (const float*)d_in[12];
    const float* bv = (const float*)d_in[13];
    const float* Wr = (const float*)d_in[14];
    const float* br = (const float*)d_in[15];
    float* ws  = (float*)d_ws;
    float* out = (float*)d_out;

    hipLaunchKernelGGL(fused_mas, dim3(NBLK), dim3(256), 0, stream,
                       states, noise, W1, b1, W2, b2, Wc, bc, Wg, bg,
                       Wp, bp, Wv, bv, Wr, br, ws, out);
}